// Round 5
// baseline (143.031 us; speedup 1.0000x reference)
//
#include <hip/hip_runtime.h>
#include <math.h>

#define BB 8
#define NN 4096
#define PP 16
#define SS 200

// ws layout (floats):
// [0, X_FLOATS)          : X table as float4 {-2x,-2y,-2z, x^2+y^2+z^2}
// [X_FLOATS+0 .. +1]     : accum[0]=cub_sum, accum[1]=cd_sum
// [X_FLOATS+2 .. +129]   : colsum[B*P]
// [X_FLOATS+130]         : ticket (unsigned)
#define X_FLOATS (BB*PP*SS*4)
#define ZERO_FLOATS (2 + BB*PP + 1)

__global__ void sq_points_kernel(const float* __restrict__ scale,
                                 const float* __restrict__ shape_eps,
                                 const float* __restrict__ etas,
                                 const float* __restrict__ omegas,
                                 float4* __restrict__ X,
                                 float* __restrict__ zero_region) {
    int idx = blockIdx.x * blockDim.x + threadIdx.x;   // (b*P + p)*S + s
    // zero accum[2] + colsum[128] + ticket (runs before main_kernel in stream)
    if (blockIdx.x == 0 && threadIdx.x < ZERO_FLOATS) zero_region[threadIdx.x] = 0.f;
    if (idx >= BB * PP * SS) return;
    int bp = idx / SS;
    float eta = etas[idx];
    float om  = omegas[idx];
    if (eta == 0.f) eta = 1e-6f;
    if (om  == 0.f) om  = 1e-6f;
    float a1 = scale[bp*3+0], a2 = scale[bp*3+1], a3 = scale[bp*3+2];
    float e1 = shape_eps[bp*2+0], e2 = shape_eps[bp*2+1];
    float ce = cosf(eta), se = sinf(eta);
    float co = cosf(om),  so = sinf(om);
    auto fexp = [](float x, float p) {
        float sg = (x > 0.f) ? 1.f : ((x < 0.f) ? -1.f : 0.f);
        return sg * powf(fabsf(x), p);
    };
    float fce = fexp(ce, e1);
    float x = a1 * fce * fexp(co, e2);
    float y = a2 * fce * fexp(so, e2);
    float z = a3 * fexp(se, e1);
    auto clampv = [](float v) {
        return ((v > 0.f) ? 1.f : -1.f) * fmaxf(fabsf(v), 1e-6f);
    };
    x = clampv(x); y = clampv(y); z = clampv(z);
    float xsq = x*x + y*y + z*z;
    X[idx] = make_float4(-2.f*x, -2.f*y, -2.f*z, xsq);
}

// grid = B*P*16 blocks of 256 threads; 1 point per thread.
// Sample table staged in LDS; broadcast ds_reads (in-order lgkmcnt -> the
// compiler pipelines them). colsum fused; finalize fused via atomic ticket.
__global__ __launch_bounds__(256) void main_kernel(
    const float* __restrict__ pc, const float* __restrict__ normals,
    const float* __restrict__ trans, const float* __restrict__ rotate,
    const float* __restrict__ scale, const float* __restrict__ assign,
    const float4* __restrict__ Xd, float* __restrict__ accum,
    float* __restrict__ colsum, unsigned* __restrict__ ticket,
    const float* __restrict__ exist, float* __restrict__ out, int nblocks) {
    __shared__ float4 Xs[SS];
    __shared__ float rc[4], rd[4], ra[4];
    __shared__ float bce_s[128], sq_s[128];
    __shared__ int is_last;

    int blk = blockIdx.x;
    int chunk = blk & 15;          // 256-point chunk
    int p = (blk >> 4) & 15;
    int b = blk >> 8;
    int bp = b * PP + p;

    const float4* __restrict__ Xp = Xd + (size_t)bp * SS;
    if (threadIdx.x < SS) Xs[threadIdx.x] = Xp[threadIdx.x];

    // wave-uniform primitive params -> scalar regs
    float tx = trans[bp*3+0], ty = trans[bp*3+1], tz = trans[bp*3+2];
    float R0 = rotate[bp*9+0], R1 = rotate[bp*9+1], R2 = rotate[bp*9+2];
    float R3 = rotate[bp*9+3], R4 = rotate[bp*9+4], R5 = rotate[bp*9+5];
    float R6 = rotate[bp*9+6], R7 = rotate[bp*9+7], R8 = rotate[bp*9+8];
    float sx = scale[bp*3+0], sy = scale[bp*3+1], sz = scale[bp*3+2];

    int n = chunk * 256 + threadIdx.x;
    size_t base = ((size_t)b * NN + n) * 3;
    float px = pc[base+0], py = pc[base+1], pz = pc[base+2];
    float qx = normals[base+0], qy = normals[base+1], qz = normals[base+2];
    float aw = assign[((size_t)b * NN + n) * PP + p];

    float d0 = px - tx, d1 = py - ty, d2 = pz - tz;
    float y0 = R0*d0 + R3*d1 + R6*d2;
    float y1 = R1*d0 + R4*d1 + R7*d2;
    float y2 = R2*d0 + R5*d1 + R8*d2;
    float e0 = qx - tx, e1 = qy - ty, e2 = qz - tz;
    float m0 = R0*e0 + R3*e1 + R6*e2;
    float m1 = R1*e0 + R4*e1 + R7*e2;
    float m2 = R2*e0 + R5*e1 + R8*e2;

    // ---- cuboid loss ----
    float rn = 1.f / fmaxf(sqrtf(m0*m0 + m1*m1 + m2*m2), 1e-4f);
    float s0 = -m0*rn, s1 = m0*rn, s2 = -m1*rn, s3 = m1*rn, s4 = -m2*rn, s5 = m2*rn;
    int fidx = 0; float best = s0;
    if (s1 > best) { best = s1; fidx = 1; }
    if (s2 > best) { best = s2; fidx = 2; }
    if (s3 > best) { best = s3; fidx = 3; }
    if (s4 > best) { best = s4; fidx = 4; }
    if (s5 > best) { best = s5; fidx = 5; }
    int axis = fidx >> 1;
    float sgn = (fidx & 1) ? 1.f : -1.f;
    float pjx = fminf(fmaxf(y0, -sx), sx);
    float pjy = fminf(fmaxf(y1, -sy), sy);
    float pjz = fminf(fmaxf(y2, -sz), sz);
    if (axis == 0)      pjx = sgn * sx;
    else if (axis == 1) pjy = sgn * sy;
    else                pjz = sgn * sz;
    float dxx = pjx - y0, dyy = pjy - y1, dzz = pjz - y2;
    float cubd = dxx*dxx + dyy*dyy + dzz*dzz;
    float ysq = y0*y0 + y1*y1 + y2*y2;

    __syncthreads();   // Xs ready

    // ---- chamfer: 200 samples from LDS, 4 independent min-chains ----
    float mm[4] = {1e30f, 1e30f, 1e30f, 1e30f};
#pragma unroll 2
    for (int s = 0; s < SS; s += 4) {
        float4 x0 = Xs[s+0], x1 = Xs[s+1], x2 = Xs[s+2], x3 = Xs[s+3];
        mm[0] = fminf(mm[0], fmaf(x0.x, y0, fmaf(x0.y, y1, fmaf(x0.z, y2, x0.w))));
        mm[1] = fminf(mm[1], fmaf(x1.x, y0, fmaf(x1.y, y1, fmaf(x1.z, y2, x1.w))));
        mm[2] = fminf(mm[2], fmaf(x2.x, y0, fmaf(x2.y, y1, fmaf(x2.z, y2, x2.w))));
        mm[3] = fminf(mm[3], fmaf(x3.x, y0, fmaf(x3.y, y1, fmaf(x3.z, y2, x3.w))));
    }
    float mn = fminf(fminf(mm[0], mm[1]), fminf(mm[2], mm[3]));
    float D = fmaxf(mn + ysq, 0.f);

    float acc_cub = cubd * aw;
    float acc_cd  = D * aw;
    float acc_as  = aw;

    // block reduction (3 values)
#pragma unroll
    for (int off = 32; off > 0; off >>= 1) {
        acc_cub += __shfl_down(acc_cub, off, 64);
        acc_cd  += __shfl_down(acc_cd,  off, 64);
        acc_as  += __shfl_down(acc_as,  off, 64);
    }
    int wave = threadIdx.x >> 6, lane = threadIdx.x & 63;
    if (lane == 0) { rc[wave] = acc_cub; rd[wave] = acc_cd; ra[wave] = acc_as; }
    __syncthreads();
    if (threadIdx.x == 0) {
        atomicAdd(&accum[0], rc[0]+rc[1]+rc[2]+rc[3]);
        atomicAdd(&accum[1], rd[0]+rd[1]+rd[2]+rd[3]);
        atomicAdd(&colsum[bp], ra[0]+ra[1]+ra[2]+ra[3]);
        __threadfence();
        unsigned old = atomicAdd(ticket, 1u);
        is_last = (old == (unsigned)(nblocks - 1)) ? 1 : 0;
    }
    __syncthreads();
    if (is_last) {
        // ---- fused finalize (existence BCE + sparsity + combine) ----
        int t = threadIdx.x;
        if (t < 128) {
            float cs = atomicAdd(&colsum[t], 0.f);   // L2-coherent read
            float gt = (cs > 24.0f) ? 1.f : 0.f;
            float pe = exist[t];
            float lg  = fmaxf(logf(pe), -100.f);
            float lg1 = fmaxf(logf(1.f - pe), -100.f);
            bce_s[t] = -(gt * lg + (1.f - gt) * lg1);
            sq_s[t] = sqrtf(cs / (float)NN + 0.01f);
        }
        __syncthreads();
        if (t == 0) {
            float ext = 0.f;
            for (int i = 0; i < 128; i++) ext += bce_s[i];
            ext /= 128.f;
            float sps = 0.f;
            for (int bb = 0; bb < 8; bb++) {
                float mb = 0.f;
                for (int pp2 = 0; pp2 < 16; pp2++) mb += sq_s[bb*16 + pp2];
                mb /= 16.f;
                sps += mb * mb;
            }
            sps /= 8.f;
            float cub = atomicAdd(&accum[0], 0.f) / (float)(BB * NN);
            float p2p = atomicAdd(&accum[1], 0.f) / (float)(BB * NN);
            float cd  = 2.f * p2p;
            out[0] = 1.0f * cub + 1.0f * cd + 0.1f * ext + 0.1f * sps;
        }
    }
}

extern "C" void kernel_launch(void* const* d_in, const int* in_sizes, int n_in,
                              void* d_out, int out_size, void* d_ws, size_t ws_size,
                              hipStream_t stream) {
    const float* pc        = (const float*)d_in[0];
    const float* normals   = (const float*)d_in[1];
    const float* trans     = (const float*)d_in[2];
    const float* rotate    = (const float*)d_in[3];
    const float* scale     = (const float*)d_in[4];
    const float* shape_eps = (const float*)d_in[5];
    const float* exist     = (const float*)d_in[6];
    const float* assign    = (const float*)d_in[7];
    const float* etas      = (const float*)d_in[8];
    const float* omegas    = (const float*)d_in[9];

    float* ws = (float*)d_ws;
    float4* X = (float4*)ws;
    float* accum  = ws + X_FLOATS;
    float* colsum = accum + 2;
    unsigned* ticket = (unsigned*)(colsum + BB*PP);

    const int nblocks = BB * PP * 16;   // 2048
    sq_points_kernel<<<(BB*PP*SS + 255)/256, 256, 0, stream>>>(
        scale, shape_eps, etas, omegas, X, accum /* zeroes accum+colsum+ticket */);
    main_kernel<<<nblocks, 256, 0, stream>>>(
        pc, normals, trans, rotate, scale, assign, X, accum, colsum, ticket,
        exist, (float*)d_out, nblocks);
}

// Round 6
// 102.110 us; speedup vs baseline: 1.4007x; 1.4007x over previous
//
#include <hip/hip_runtime.h>
#include <math.h>

#define BB 8
#define NN 4096
#define PP 16
#define SS 200

// ws layout (floats):
// [0, X_FLOATS)          : X table as float4 {-2x,-2y,-2z, x^2+y^2+z^2}
// [X_FLOATS+0 .. +1]     : accum[0]=cub_sum, accum[1]=cd_sum
// [X_FLOATS+2 .. +129]   : colsum[B*P]
#define X_FLOATS (BB*PP*SS*4)
#define ZERO_FLOATS (2 + BB*PP)

__global__ void sq_points_kernel(const float* __restrict__ scale,
                                 const float* __restrict__ shape_eps,
                                 const float* __restrict__ etas,
                                 const float* __restrict__ omegas,
                                 float4* __restrict__ X,
                                 float* __restrict__ zero_region) {
    int idx = blockIdx.x * blockDim.x + threadIdx.x;   // (b*P + p)*S + s
    if (blockIdx.x == 0 && threadIdx.x < ZERO_FLOATS) zero_region[threadIdx.x] = 0.f;
    if (idx >= BB * PP * SS) return;
    int bp = idx / SS;
    float eta = etas[idx];
    float om  = omegas[idx];
    if (eta == 0.f) eta = 1e-6f;
    if (om  == 0.f) om  = 1e-6f;
    float a1 = scale[bp*3+0], a2 = scale[bp*3+1], a3 = scale[bp*3+2];
    float e1 = shape_eps[bp*2+0], e2 = shape_eps[bp*2+1];
    float ce = cosf(eta), se = sinf(eta);
    float co = cosf(om),  so = sinf(om);
    auto fexp = [](float x, float p) {
        float sg = (x > 0.f) ? 1.f : ((x < 0.f) ? -1.f : 0.f);
        return sg * powf(fabsf(x), p);
    };
    float fce = fexp(ce, e1);
    float x = a1 * fce * fexp(co, e2);
    float y = a2 * fce * fexp(so, e2);
    float z = a3 * fexp(se, e1);
    auto clampv = [](float v) {
        return ((v > 0.f) ? 1.f : -1.f) * fmaxf(fabsf(v), 1e-6f);
    };
    x = clampv(x); y = clampv(y); z = clampv(z);
    float xsq = x*x + y*y + z*z;
    X[idx] = make_float4(-2.f*x, -2.f*y, -2.f*z, xsq);
}

// grid = B*P*4 = 512 blocks of 256 threads; 4 points per thread.
// Sample table in LDS (broadcast ds_read_b128, in-order lgkmcnt); each
// ds_read feeds 4 points -> VALU-bound inner loop. colsum fused.
__global__ __launch_bounds__(256) void main_kernel(
    const float* __restrict__ pc, const float* __restrict__ normals,
    const float* __restrict__ trans, const float* __restrict__ rotate,
    const float* __restrict__ scale, const float* __restrict__ assign,
    const float4* __restrict__ Xd, float* __restrict__ accum,
    float* __restrict__ colsum) {
    __shared__ float4 Xs[SS];
    __shared__ float rc[4], rd[4], ra[4];

    int blk = blockIdx.x;
    int chunk = blk & 3;           // 1024-point chunk
    int p = (blk >> 2) & 15;
    int b = blk >> 6;
    int bp = b * PP + p;

    const float4* __restrict__ Xp = Xd + (size_t)bp * SS;
    if (threadIdx.x < SS) Xs[threadIdx.x] = Xp[threadIdx.x];

    // wave-uniform primitive params -> scalar regs
    float tx = trans[bp*3+0], ty = trans[bp*3+1], tz = trans[bp*3+2];
    float R0 = rotate[bp*9+0], R1 = rotate[bp*9+1], R2 = rotate[bp*9+2];
    float R3 = rotate[bp*9+3], R4 = rotate[bp*9+4], R5 = rotate[bp*9+5];
    float R6 = rotate[bp*9+6], R7 = rotate[bp*9+7], R8 = rotate[bp*9+8];
    float sx = scale[bp*3+0], sy = scale[bp*3+1], sz = scale[bp*3+2];

    float y0[4], y1[4], y2[4], ysq[4], aw[4];
    float acc_cub = 0.f, acc_as = 0.f;
#pragma unroll
    for (int j = 0; j < 4; j++) {
        int n = chunk * 1024 + j * 256 + threadIdx.x;
        size_t base = ((size_t)b * NN + n) * 3;
        float px = pc[base+0], py = pc[base+1], pz = pc[base+2];
        float qx = normals[base+0], qy = normals[base+1], qz = normals[base+2];
        aw[j] = assign[((size_t)b * NN + n) * PP + p];

        float d0 = px - tx, d1 = py - ty, d2 = pz - tz;
        y0[j] = R0*d0 + R3*d1 + R6*d2;
        y1[j] = R1*d0 + R4*d1 + R7*d2;
        y2[j] = R2*d0 + R5*d1 + R8*d2;
        float e0 = qx - tx, e1 = qy - ty, e2 = qz - tz;
        float m0 = R0*e0 + R3*e1 + R6*e2;
        float m1 = R1*e0 + R4*e1 + R7*e2;
        float m2 = R2*e0 + R5*e1 + R8*e2;

        // ---- cuboid loss ----
        float rn = 1.f / fmaxf(sqrtf(m0*m0 + m1*m1 + m2*m2), 1e-4f);
        float s0 = -m0*rn, s1 = m0*rn, s2 = -m1*rn, s3 = m1*rn, s4 = -m2*rn, s5 = m2*rn;
        int fidx = 0; float best = s0;
        if (s1 > best) { best = s1; fidx = 1; }
        if (s2 > best) { best = s2; fidx = 2; }
        if (s3 > best) { best = s3; fidx = 3; }
        if (s4 > best) { best = s4; fidx = 4; }
        if (s5 > best) { best = s5; fidx = 5; }
        int axis = fidx >> 1;
        float sgn = (fidx & 1) ? 1.f : -1.f;
        float pjx = fminf(fmaxf(y0[j], -sx), sx);
        float pjy = fminf(fmaxf(y1[j], -sy), sy);
        float pjz = fminf(fmaxf(y2[j], -sz), sz);
        if (axis == 0)      pjx = sgn * sx;
        else if (axis == 1) pjy = sgn * sy;
        else                pjz = sgn * sz;
        float dxx = pjx - y0[j], dyy = pjy - y1[j], dzz = pjz - y2[j];
        acc_cub += (dxx*dxx + dyy*dyy + dzz*dzz) * aw[j];
        ysq[j] = y0[j]*y0[j] + y1[j]*y1[j] + y2[j]*y2[j];
        acc_as += aw[j];
    }

    __syncthreads();   // Xs ready

    // ---- chamfer: 200 samples from LDS; 2 chains x 4 points ----
    float mmA[4] = {1e30f, 1e30f, 1e30f, 1e30f};
    float mmB[4] = {1e30f, 1e30f, 1e30f, 1e30f};
#pragma unroll 2
    for (int s = 0; s < SS; s += 2) {
        float4 xa = Xs[s+0], xb = Xs[s+1];
#pragma unroll
        for (int j = 0; j < 4; j++) {
            mmA[j] = fminf(mmA[j], fmaf(xa.x, y0[j], fmaf(xa.y, y1[j], fmaf(xa.z, y2[j], xa.w))));
            mmB[j] = fminf(mmB[j], fmaf(xb.x, y0[j], fmaf(xb.y, y1[j], fmaf(xb.z, y2[j], xb.w))));
        }
    }
    float acc_cd = 0.f;
#pragma unroll
    for (int j = 0; j < 4; j++) {
        float mn = fminf(mmA[j], mmB[j]);
        acc_cd += fmaxf(mn + ysq[j], 0.f) * aw[j];
    }

    // block reduction (3 values)
#pragma unroll
    for (int off = 32; off > 0; off >>= 1) {
        acc_cub += __shfl_down(acc_cub, off, 64);
        acc_cd  += __shfl_down(acc_cd,  off, 64);
        acc_as  += __shfl_down(acc_as,  off, 64);
    }
    int wave = threadIdx.x >> 6, lane = threadIdx.x & 63;
    if (lane == 0) { rc[wave] = acc_cub; rd[wave] = acc_cd; ra[wave] = acc_as; }
    __syncthreads();
    if (threadIdx.x == 0) {
        atomicAdd(&accum[0], rc[0]+rc[1]+rc[2]+rc[3]);
        atomicAdd(&accum[1], rd[0]+rd[1]+rd[2]+rd[3]);
        atomicAdd(&colsum[bp], ra[0]+ra[1]+ra[2]+ra[3]);
    }
}

__global__ void finalize_kernel(const float* __restrict__ exist,
                                const float* __restrict__ colsum,
                                const float* __restrict__ accum,
                                float* __restrict__ out) {
    int t = threadIdx.x;  // 0..127 -> b*16+p
    __shared__ float bce_s[128], sq_s[128];
    float cs = colsum[t];
    float gt = (cs > 24.0f) ? 1.f : 0.f;
    float pe = exist[t];
    float lg  = fmaxf(logf(pe), -100.f);
    float lg1 = fmaxf(logf(1.f - pe), -100.f);
    bce_s[t] = -(gt * lg + (1.f - gt) * lg1);
    sq_s[t] = sqrtf(cs / (float)NN + 0.01f);
    __syncthreads();
    if (t == 0) {
        float ext = 0.f;
        for (int i = 0; i < 128; i++) ext += bce_s[i];
        ext /= 128.f;
        float sps = 0.f;
        for (int b = 0; b < 8; b++) {
            float mb = 0.f;
            for (int p = 0; p < 16; p++) mb += sq_s[b*16 + p];
            mb /= 16.f;
            sps += mb * mb;
        }
        sps /= 8.f;
        float cub = accum[0] / (float)(BB * NN);
        float p2p = accum[1] / (float)(BB * NN);
        float cd  = 2.f * p2p;
        out[0] = 1.0f * cub + 1.0f * cd + 0.1f * ext + 0.1f * sps;
    }
}

extern "C" void kernel_launch(void* const* d_in, const int* in_sizes, int n_in,
                              void* d_out, int out_size, void* d_ws, size_t ws_size,
                              hipStream_t stream) {
    const float* pc        = (const float*)d_in[0];
    const float* normals   = (const float*)d_in[1];
    const float* trans     = (const float*)d_in[2];
    const float* rotate    = (const float*)d_in[3];
    const float* scale     = (const float*)d_in[4];
    const float* shape_eps = (const float*)d_in[5];
    const float* exist     = (const float*)d_in[6];
    const float* assign    = (const float*)d_in[7];
    const float* etas      = (const float*)d_in[8];
    const float* omegas    = (const float*)d_in[9];

    float* ws = (float*)d_ws;
    float4* X = (float4*)ws;
    float* accum  = ws + X_FLOATS;
    float* colsum = accum + 2;

    sq_points_kernel<<<(BB*PP*SS + 255)/256, 256, 0, stream>>>(
        scale, shape_eps, etas, omegas, X, accum /* zeroes accum+colsum */);
    main_kernel<<<BB*PP*4, 256, 0, stream>>>(
        pc, normals, trans, rotate, scale, assign, X, accum, colsum);
    finalize_kernel<<<1, 128, 0, stream>>>(exist, colsum, accum, (float*)d_out);
}

// Round 7
// 89.179 us; speedup vs baseline: 1.6039x; 1.1450x over previous
//
#include <hip/hip_runtime.h>
#include <math.h>

#define BB 8
#define NN 4096
#define PP 16
#define SS 200
#define NCHUNK 4                  // 1024-point chunks per (b,p)
#define NBLK (BB*PP*NCHUNK)       // 512 blocks

// ws layout (floats): cub_part[512] | cd_part[512] | colsum_part[512]
// No pre-zeroing needed: every slot is unconditionally written by its block.

// grid = 512 blocks of 256 threads; block = (b,p,chunk); 4 points/thread.
// Samples computed in-block directly into LDS (no global X table).
__global__ __launch_bounds__(256) void main_kernel(
    const float* __restrict__ pc, const float* __restrict__ normals,
    const float* __restrict__ trans, const float* __restrict__ rotate,
    const float* __restrict__ scale, const float* __restrict__ shape_eps,
    const float* __restrict__ assign,
    const float* __restrict__ etas, const float* __restrict__ omegas,
    float* __restrict__ cub_part, float* __restrict__ cd_part,
    float* __restrict__ colsum_part) {
    __shared__ float4 Xs[SS];
    __shared__ float rc[4], rd[4], ra[4];

    int blk = blockIdx.x;
    int chunk = blk & (NCHUNK-1);
    int bp = blk >> 2;             // b*PP + p
    int b = bp >> 4;
    int p = bp & 15;

    // ---- in-block sample table (threads 0..SS-1) ----
    if (threadIdx.x < SS) {
        int idx = bp * SS + threadIdx.x;
        float eta = etas[idx];
        float om  = omegas[idx];
        if (eta == 0.f) eta = 1e-6f;
        if (om  == 0.f) om  = 1e-6f;
        float a1 = scale[bp*3+0], a2 = scale[bp*3+1], a3 = scale[bp*3+2];
        float e1 = shape_eps[bp*2+0], e2 = shape_eps[bp*2+1];
        float ce = cosf(eta), se = sinf(eta);
        float co = cosf(om),  so = sinf(om);
        auto fexp = [](float x, float pw) {
            float sg = (x > 0.f) ? 1.f : ((x < 0.f) ? -1.f : 0.f);
            return sg * powf(fabsf(x), pw);
        };
        float fce = fexp(ce, e1);
        float x = a1 * fce * fexp(co, e2);
        float y = a2 * fce * fexp(so, e2);
        float z = a3 * fexp(se, e1);
        auto clampv = [](float v) {
            return ((v > 0.f) ? 1.f : -1.f) * fmaxf(fabsf(v), 1e-6f);
        };
        x = clampv(x); y = clampv(y); z = clampv(z);
        float xsq = x*x + y*y + z*z;
        Xs[threadIdx.x] = make_float4(-2.f*x, -2.f*y, -2.f*z, xsq);
    }

    // wave-uniform primitive params -> scalar regs
    float tx = trans[bp*3+0], ty = trans[bp*3+1], tz = trans[bp*3+2];
    float R0 = rotate[bp*9+0], R1 = rotate[bp*9+1], R2 = rotate[bp*9+2];
    float R3 = rotate[bp*9+3], R4 = rotate[bp*9+4], R5 = rotate[bp*9+5];
    float R6 = rotate[bp*9+6], R7 = rotate[bp*9+7], R8 = rotate[bp*9+8];
    float sx = scale[bp*3+0], sy = scale[bp*3+1], sz = scale[bp*3+2];

    float y0[4], y1[4], y2[4], ysq[4], aw[4];
    float acc_cub = 0.f, acc_as = 0.f;
#pragma unroll
    for (int j = 0; j < 4; j++) {
        int n = chunk * 1024 + j * 256 + threadIdx.x;
        size_t base = ((size_t)b * NN + n) * 3;
        float px = pc[base+0], py = pc[base+1], pz = pc[base+2];
        float qx = normals[base+0], qy = normals[base+1], qz = normals[base+2];
        aw[j] = assign[((size_t)b * NN + n) * PP + p];

        float d0 = px - tx, d1 = py - ty, d2 = pz - tz;
        y0[j] = R0*d0 + R3*d1 + R6*d2;
        y1[j] = R1*d0 + R4*d1 + R7*d2;
        y2[j] = R2*d0 + R5*d1 + R8*d2;
        float e0 = qx - tx, e1 = qy - ty, e2 = qz - tz;
        float m0 = R0*e0 + R3*e1 + R6*e2;
        float m1 = R1*e0 + R4*e1 + R7*e2;
        float m2 = R2*e0 + R5*e1 + R8*e2;

        // ---- cuboid loss (no Xs dependency; overlaps sample compute) ----
        float rn = 1.f / fmaxf(sqrtf(m0*m0 + m1*m1 + m2*m2), 1e-4f);
        float s0 = -m0*rn, s1 = m0*rn, s2 = -m1*rn, s3 = m1*rn, s4 = -m2*rn, s5 = m2*rn;
        int fidx = 0; float best = s0;
        if (s1 > best) { best = s1; fidx = 1; }
        if (s2 > best) { best = s2; fidx = 2; }
        if (s3 > best) { best = s3; fidx = 3; }
        if (s4 > best) { best = s4; fidx = 4; }
        if (s5 > best) { best = s5; fidx = 5; }
        int axis = fidx >> 1;
        float sgn = (fidx & 1) ? 1.f : -1.f;
        float pjx = fminf(fmaxf(y0[j], -sx), sx);
        float pjy = fminf(fmaxf(y1[j], -sy), sy);
        float pjz = fminf(fmaxf(y2[j], -sz), sz);
        if (axis == 0)      pjx = sgn * sx;
        else if (axis == 1) pjy = sgn * sy;
        else                pjz = sgn * sz;
        float dxx = pjx - y0[j], dyy = pjy - y1[j], dzz = pjz - y2[j];
        acc_cub += (dxx*dxx + dyy*dyy + dzz*dzz) * aw[j];
        ysq[j] = y0[j]*y0[j] + y1[j]*y1[j] + y2[j]*y2[j];
        acc_as += aw[j];
    }

    __syncthreads();   // Xs ready

    // ---- chamfer: 200 samples from LDS, 8 samples/group (deep ds pipeline),
    //      8 independent min-chains x 4 points ----
    float mmA[4] = {1e30f, 1e30f, 1e30f, 1e30f};
    float mmB[4] = {1e30f, 1e30f, 1e30f, 1e30f};
#pragma unroll 4
    for (int s = 0; s < SS; s += 2) {
        float4 xa = Xs[s+0], xb = Xs[s+1];
#pragma unroll
        for (int j = 0; j < 4; j++) {
            mmA[j] = fminf(mmA[j], fmaf(xa.x, y0[j], fmaf(xa.y, y1[j], fmaf(xa.z, y2[j], xa.w))));
            mmB[j] = fminf(mmB[j], fmaf(xb.x, y0[j], fmaf(xb.y, y1[j], fmaf(xb.z, y2[j], xb.w))));
        }
    }
    float acc_cd = 0.f;
#pragma unroll
    for (int j = 0; j < 4; j++) {
        float mn = fminf(mmA[j], mmB[j]);
        acc_cd += fmaxf(mn + ysq[j], 0.f) * aw[j];
    }

    // block reduction (3 values), then one plain store per block (no atomics)
#pragma unroll
    for (int off = 32; off > 0; off >>= 1) {
        acc_cub += __shfl_down(acc_cub, off, 64);
        acc_cd  += __shfl_down(acc_cd,  off, 64);
        acc_as  += __shfl_down(acc_as,  off, 64);
    }
    int wave = threadIdx.x >> 6, lane = threadIdx.x & 63;
    if (lane == 0) { rc[wave] = acc_cub; rd[wave] = acc_cd; ra[wave] = acc_as; }
    __syncthreads();
    if (threadIdx.x == 0) {
        cub_part[blk]    = rc[0]+rc[1]+rc[2]+rc[3];
        cd_part[blk]     = rd[0]+rd[1]+rd[2]+rd[3];
        colsum_part[blk] = ra[0]+ra[1]+ra[2]+ra[3];
    }
}

__global__ void finalize_kernel(const float* __restrict__ exist,
                                const float* __restrict__ cub_part,
                                const float* __restrict__ cd_part,
                                const float* __restrict__ colsum_part,
                                float* __restrict__ out) {
    int t = threadIdx.x;   // 256 threads
    __shared__ float bce_s[128], sq_s[128], rcub[4], rcd[4];

    float c1 = cub_part[t] + cub_part[t + 256];
    float c2 = cd_part[t]  + cd_part[t + 256];
#pragma unroll
    for (int off = 32; off > 0; off >>= 1) {
        c1 += __shfl_down(c1, off, 64);
        c2 += __shfl_down(c2, off, 64);
    }
    int wave = t >> 6, lane = t & 63;
    if (lane == 0) { rcub[wave] = c1; rcd[wave] = c2; }

    if (t < 128) {
        float cs = colsum_part[t*4+0] + colsum_part[t*4+1]
                 + colsum_part[t*4+2] + colsum_part[t*4+3];
        float gt = (cs > 24.0f) ? 1.f : 0.f;
        float pe = exist[t];
        float lg  = fmaxf(logf(pe), -100.f);
        float lg1 = fmaxf(logf(1.f - pe), -100.f);
        bce_s[t] = -(gt * lg + (1.f - gt) * lg1);
        sq_s[t] = sqrtf(cs / (float)NN + 0.01f);
    }
    __syncthreads();
    if (t == 0) {
        float ext = 0.f;
        for (int i = 0; i < 128; i++) ext += bce_s[i];
        ext /= 128.f;
        float sps = 0.f;
        for (int bb = 0; bb < 8; bb++) {
            float mb = 0.f;
            for (int pp2 = 0; pp2 < 16; pp2++) mb += sq_s[bb*16 + pp2];
            mb /= 16.f;
            sps += mb * mb;
        }
        sps /= 8.f;
        float cub = (rcub[0]+rcub[1]+rcub[2]+rcub[3]) / (float)(BB * NN);
        float p2p = (rcd[0]+rcd[1]+rcd[2]+rcd[3]) / (float)(BB * NN);
        float cd  = 2.f * p2p;
        out[0] = 1.0f * cub + 1.0f * cd + 0.1f * ext + 0.1f * sps;
    }
}

extern "C" void kernel_launch(void* const* d_in, const int* in_sizes, int n_in,
                              void* d_out, int out_size, void* d_ws, size_t ws_size,
                              hipStream_t stream) {
    const float* pc        = (const float*)d_in[0];
    const float* normals   = (const float*)d_in[1];
    const float* trans     = (const float*)d_in[2];
    const float* rotate    = (const float*)d_in[3];
    const float* scale     = (const float*)d_in[4];
    const float* shape_eps = (const float*)d_in[5];
    const float* exist     = (const float*)d_in[6];
    const float* assign    = (const float*)d_in[7];
    const float* etas      = (const float*)d_in[8];
    const float* omegas    = (const float*)d_in[9];

    float* ws = (float*)d_ws;
    float* cub_part    = ws;
    float* cd_part     = ws + NBLK;
    float* colsum_part = ws + 2*NBLK;

    main_kernel<<<NBLK, 256, 0, stream>>>(
        pc, normals, trans, rotate, scale, shape_eps, assign, etas, omegas,
        cub_part, cd_part, colsum_part);
    finalize_kernel<<<1, 256, 0, stream>>>(
        exist, cub_part, cd_part, colsum_part, (float*)d_out);
}